// Round 7
// baseline (183.546 us; speedup 1.0000x reference)
//
#include <hip/hip_runtime.h>

// ForwardKinematics: B=65536 bodies, N=24 joints, compile-time parent tree.
//
// Round 10 = round 9 (DPP register chain, 4 waves/SIMD, full-line staged
// flushes) with the input burst replaced by PER-CHUNK PIPELINED loads.
//
// Round-9 post-mortem: three structurally different kernels (r3/r8/r9) all
// plateau at 53-59us ~= 3.6 TB/s. Common structure: one resident generation
// (4096 waves) and a monolithic 19-load input burst pinned above the chain
// -> chip-wide serial phases: ~12us read-only prefix, ~4us VALU, then a
// long write drain. Reads and writes never mix, so neither stream runs at
// its ceiling concurrently.
//
// Fix: loads move to rel-chunk granularity (4 joints = 12 f4/quad = 3
// loads/lane), 3-deep rolling buffer, chunk c+2's loads issued at the start
// of chunk c's compute, each issue followed by sched_barrier(0) so the
// scheduler cannot re-sink them (r6 failure mode; r8/r9 proved the barrier
// pins loads). Compiler emits counted vmcnt waits (never 0). Every wave now
// alternates load-issue / FMA / store-flush at ~300-cycle granularity ->
// read and write streams interleave chip-wide even in one generation;
// 2-chunks-ahead (~2500 cy at 4 waves/SIMD) covers cold-HBM latency.
// Input regs drop 76 -> 36 (3 chunks x 12), VGPR ~100, still 4 waves/SIMD.
//
// Carried: 4 lanes/body; DPP quad_perm broadcasts at compile-time
// (owner,reg,elem) coords; parent joint positions kept in per-lane jx/jy/jz
// (broadcast values, short liveness) so only the CURRENT chunk's buffer is
// DPP-sourced; rel staged at stride-17 f4 in LDS, flushed as 4x 1KB
// full-line instructions per chunk; posed staged stride-19, 5 full-line
// instructions; one wave/block, all ordering via wave-synchronous fences.

typedef float f32x4 __attribute__((ext_vector_type(4)));
typedef int   i32x4 __attribute__((ext_vector_type(4)));

constexpr int PARENTS[24] = {-1, 0, 0, 0, 1, 2, 3, 4, 5, 6, 7, 8,
                             9, 9, 9, 12, 13, 14, 16, 17, 18, 19, 20, 21};

constexpr int RELW       = 17;            // f4 per body, rel chunk region
constexpr int REL_WORDS  = 16 * RELW * 4; // 1088 words
constexpr int POSW       = 76;            // words per body, posed region

__device__ __forceinline__ void wave_sync() {
    asm volatile("" ::: "memory");
    __builtin_amdgcn_wave_barrier();
    asm volatile("" ::: "memory");
}

// Broadcast lane O's (within each quad) value of x to the whole quad.
template<int O>
__device__ __forceinline__ float qbf(int x) {
    return __builtin_bit_cast(float,
        __builtin_amdgcn_update_dpp(0, x, (O) * 0x55, 0xF, 0xF, true));
}

// Chunk-local input layout: chunk c covers joints 4c..4c+3.
//   rot floats e=0..35 of the chunk -> f4 slot k=e>>2 (0..8)
//   jts floats g=0..11 of the chunk -> f4 slot 9+(g>>2) (9..11)
// Slot k owned by lane k&3, local reg u=k>>2 (0..2). Lane r's loads:
//   u=0: rot4[9c + r]; u=1: rot4[9c+4+r]; u=2: r==0 ? rot4[9c+8]
//                                               : jt4[3c + r-1].
#define RBC(I, m) qbf<(((9*((I)&3)+(m)) >> 2) & 3)>( \
    buf[((I)>>2) % 3][((9*((I)&3)+(m)) >> 2) >> 2][(9*((I)&3)+(m)) & 3] )
#define JBC(I, m) qbf<((1 + ((3*((I)&3)+(m)) >> 2)) & 3)>( \
    buf[((I)>>2) % 3][2][(3*((I)&3)+(m)) & 3] )

template<int C>
__device__ __forceinline__ void load_chunk(i32x4 (&buf)[3][3],
    const i32x4* rot4, const i32x4* cbase, int cstep, int r)
{
    buf[C % 3][0] = rot4[9*C + r];
    buf[C % 3][1] = rot4[9*C + 4 + r];
    buf[C % 3][2] = cbase[C * cstep];      // lane0: rot slot 9C+8; else jts
}

template<int I>
__device__ __forceinline__ void chain_step(
    const i32x4 (&buf)[3][3],
    float (&jx)[24], float (&jy)[24], float (&jz)[24],
    float (&a0)[24], float (&a1)[24], float (&a2)[24], float (&tg)[24],
    int l, int q, int r, bool rowlane,
    f32x4* srel, float* sp, f32x4* relB)
{
    const float jix = JBC(I, 0), jiy = JBC(I, 1), jiz = JBC(I, 2);
    jx[I] = jix; jy[I] = jiy; jz[I] = jiz;

    float b0, b1, b2, t;
    if constexpr (I == 0) {
        // Root: broadcast all of R_0, lane r selects its row; t = j0[r].
        // Lane 3 takes the r==2 path -> garbage, masked at the stage below.
        const float F0 = RBC(0,0), F1 = RBC(0,1), F2 = RBC(0,2),
                    F3 = RBC(0,3), F4 = RBC(0,4), F5 = RBC(0,5),
                    F6 = RBC(0,6), F7 = RBC(0,7), F8 = RBC(0,8);
        b0 = r == 0 ? F0 : (r == 1 ? F3 : F6);
        b1 = r == 0 ? F1 : (r == 1 ? F4 : F7);
        b2 = r == 0 ? F2 : (r == 1 ? F5 : F8);
        t  = r == 0 ? jix : (r == 1 ? jiy : jiz);
    } else {
        constexpr int P = PARENTS[I];
        const float R00 = RBC(I,0), R01 = RBC(I,1), R02 = RBC(I,2),
                    R10 = RBC(I,3), R11 = RBC(I,4), R12 = RBC(I,5),
                    R20 = RBC(I,6), R21 = RBC(I,7), R22 = RBC(I,8);
        const float c0 = a0[P], c1 = a1[P], c2 = a2[P];
        b0 = c0*R00 + c1*R10 + c2*R20;
        b1 = c0*R01 + c1*R11 + c2*R21;
        b2 = c0*R02 + c1*R12 + c2*R22;
        t  = c0*(jix - jx[P]) + c1*(jiy - jy[P]) + c2*(jiz - jz[P]) + tg[P];
    }
    a0[I] = b0; a1[I] = b1; a2[I] = b2; tg[I] = t;

    // Stage rel row in LDS: [row | t - row.j_i]; lane 3 stages (0,0,0,1).
    const float tc = t - (b0*jix + b1*jiy + b2*jiz);
    f32x4 out;
    out.x = rowlane ? b0 : 0.f;
    out.y = rowlane ? b1 : 0.f;
    out.z = rowlane ? b2 : 0.f;
    out.w = rowlane ? tc : 1.f;
    srel[q * RELW + (I & 3) * 4 + r] = out;     // stride 17 f4: conflict-free

    // posed component; lane 3 dumps into the 4-float pad (branchless).
    const int ofs = rowlane ? (3*I + r) : (72 + (I & 3));
    sp[ofs] = t;

    // Every 4th joint: flush the chunk with FULL-LINE stores.
    if constexpr ((I & 3) == 3) {
        wave_sync();                            // ds_writes before flush reads
        constexpr int c = I >> 2;               // chunk 0..5
#pragma unroll
        for (int u = 0; u < 4; ++u) {
            const int bdy = u * 4 + (l >> 4);   // 0..15
            const int f4i = l & 15;             // 0..15
            // Per instruction: 4 segments x 256 B contiguous = 8 full lines.
            relB[(size_t)bdy * 96 + c * 16 + f4i] = srel[bdy * RELW + f4i];
        }
        wave_sync();                            // flush reads before next writes
    }
}

template<int I>
__device__ __forceinline__ void chain_all(
    i32x4 (&buf)[3][3], const i32x4* rot4, const i32x4* cbase, int cstep,
    float (&jx)[24], float (&jy)[24], float (&jz)[24],
    float (&a0)[24], float (&a1)[24], float (&a2)[24], float (&tg)[24],
    int l, int q, int r, bool rowlane,
    f32x4* srel, float* sp, f32x4* relB)
{
    // At each chunk start, issue chunk c+2's loads (3 per lane), then pin
    // them with sched_barrier(0) so they cannot sink to first use.
    if constexpr ((I & 3) == 0 && (I >> 2) + 2 <= 5) {
        load_chunk<(I >> 2) + 2>(buf, rot4, cbase, cstep, r);
        __builtin_amdgcn_sched_barrier(0);
    }
    chain_step<I>(buf, jx, jy, jz, a0, a1, a2, tg,
                  l, q, r, rowlane, srel, sp, relB);
    if constexpr (I + 1 < 24)
        chain_all<I + 1>(buf, rot4, cbase, cstep, jx, jy, jz,
                         a0, a1, a2, tg, l, q, r, rowlane, srel, sp, relB);
}

__global__ __launch_bounds__(64, 4)
void fk_kernel(const float* __restrict__ rot,   // (B,24,3,3)
               const float* __restrict__ jts,   // (B,24,3)
               float* __restrict__ posed,       // (B,24,3)
               float* __restrict__ rel,         // (B,24,4,4)
               int B)
{
    __shared__ float smem[REL_WORDS + 16 * POSW];   // 2304 words = 9216 B

    const int l = threadIdx.x;                  // 0..63
    const int q = l >> 2;                       // body-in-block 0..15
    const int r = l & 3;                        // row lane (3 = bottom row)
    const bool rowlane = (r < 3);
    const int body0 = blockIdx.x * 16;
    const int body  = body0 + q;

    const i32x4* rot4 = reinterpret_cast<const i32x4*>(rot) + (size_t)body * 54;
    const i32x4* jt4  = reinterpret_cast<const i32x4*>(jts) + (size_t)body * 18;
    // Lane-dependent third-load stream: lane 0 takes rot slot 9c+8
    // (step 9/chunk), lanes 1-3 take jts slot 3c+r-1 (step 3/chunk).
    const i32x4* cbase = (r == 0) ? rot4 + 8 : jt4 + (r - 1);
    const int    cstep = (r == 0) ? 9 : 3;

    // Prime the pipeline: chunks 0 and 1 in flight before the chain.
    i32x4 buf[3][3];
    load_chunk<0>(buf, rot4, cbase, cstep, r);
    load_chunk<1>(buf, rot4, cbase, cstep, r);
    __builtin_amdgcn_sched_barrier(0);

    float jx[24], jy[24], jz[24];               // broadcast j (short liveness)
    float a0[24], a1[24], a2[24], tg[24];       // liveness-pruned by unroll
    f32x4* srel = reinterpret_cast<f32x4*>(smem);
    float* sp   = smem + REL_WORDS + q * POSW;
    f32x4* relB = reinterpret_cast<f32x4*>(rel) + (size_t)body0 * 96;

    chain_all<0>(buf, rot4, cbase, cstep, jx, jy, jz,
                 a0, a1, a2, tg, l, q, r, rowlane, srel, sp, relB);

    wave_sync();   // order posed ds_writes before transpose reads

    // posed flush: block's 16 bodies contiguous -> 288 float4 at
    // blockIdx*4608 B; 5 instructions x 1 KB contiguous (full lines).
    const f32x4* s4 = reinterpret_cast<const f32x4*>(smem + REL_WORDS); // stride 19 f4
    f32x4* pos4 = reinterpret_cast<f32x4*>(posed) + (size_t)blockIdx.x * 288;
#pragma unroll
    for (int u = 0; u < 5; ++u) {
        const int g = u * 64 + l;               // 0..319, need < 288
        if (g < 288) {
            const int bdy = g / 18;             // magic-mul division
            const int k   = g - bdy * 18;
            pos4[g] = s4[bdy * 19 + k];
        }
    }
}

extern "C" void kernel_launch(void* const* d_in, const int* in_sizes, int n_in,
                              void* d_out, int out_size, void* d_ws, size_t ws_size,
                              hipStream_t stream) {
    const float* rot = (const float*)d_in[0];   // (B,24,3,3)
    const float* jts = (const float*)d_in[1];   // (B,24,3)
    const int B = in_sizes[1] / 72;             // 24*3 floats per body

    float* posed = (float*)d_out;                       // B*24*3
    float* rel   = posed + (size_t)B * 72;              // B*24*16

    const int block = 64;                       // one wave, 16 bodies (4 lanes/body)
    const int grid  = B / 16;                   // 65536/16 = 4096 blocks
    hipLaunchKernelGGL(fk_kernel, dim3(grid), dim3(block), 0, stream,
                       rot, jts, posed, rel, B);
}